// Round 2
// baseline (18745.903 us; speedup 1.0000x reference)
//
#include <hip/hip_runtime.h>
#include <stdint.h>
#include <math.h>

#define Bn 32768
#define Ln 7
#define Tn 6
#define En 256
#define Hn 256
#define Rr 32
#define XS 36            // xbuf row stride in floats (4-aligned, not 32)
#define NEGF (-1000000000.0f)

// ---------------------------------------------------------------------------
// ws layout (floats):
//   [0, 7*65536)            : 7 transposed weight matrices WT[m][e][h]
//                             order: Wh, Wv, Wsh, Wsv, Wedge, Win, Wctx
//   [458752, 458752+B*7)    : att[b][l]
//   then 14 floats          : S[7], logS[7]
// ---------------------------------------------------------------------------

__device__ __forceinline__ uint32_t rotl32(uint32_t x, int d) {
  return (x << d) | (x >> (32 - d));
}

// JAX threefry2x32, 20 rounds (matches jax/_src/prng.py)
__device__ __forceinline__ void threefry2x32(uint32_t k0, uint32_t k1,
                                             uint32_t x0, uint32_t x1,
                                             uint32_t& o0, uint32_t& o1) {
  uint32_t k2 = k0 ^ k1 ^ 0x1BD11BDAu;
  x0 += k0; x1 += k1;
  x0 += x1; x1 = rotl32(x1, 13); x1 ^= x0;
  x0 += x1; x1 = rotl32(x1, 15); x1 ^= x0;
  x0 += x1; x1 = rotl32(x1, 26); x1 ^= x0;
  x0 += x1; x1 = rotl32(x1,  6); x1 ^= x0;
  x0 += k1; x1 += k2 + 1u;
  x0 += x1; x1 = rotl32(x1, 17); x1 ^= x0;
  x0 += x1; x1 = rotl32(x1, 29); x1 ^= x0;
  x0 += x1; x1 = rotl32(x1, 16); x1 ^= x0;
  x0 += x1; x1 = rotl32(x1, 24); x1 ^= x0;
  x0 += k2; x1 += k0 + 2u;
  x0 += x1; x1 = rotl32(x1, 13); x1 ^= x0;
  x0 += x1; x1 = rotl32(x1, 15); x1 ^= x0;
  x0 += x1; x1 = rotl32(x1, 26); x1 ^= x0;
  x0 += x1; x1 = rotl32(x1,  6); x1 ^= x0;
  x0 += k0; x1 += k1 + 3u;
  x0 += x1; x1 = rotl32(x1, 17); x1 ^= x0;
  x0 += x1; x1 = rotl32(x1, 29); x1 ^= x0;
  x0 += x1; x1 = rotl32(x1, 16); x1 ^= x0;
  x0 += x1; x1 = rotl32(x1, 24); x1 ^= x0;
  x0 += k1; x1 += k2 + 4u;
  x0 += x1; x1 = rotl32(x1, 13); x1 ^= x0;
  x0 += x1; x1 = rotl32(x1, 15); x1 ^= x0;
  x0 += x1; x1 = rotl32(x1, 26); x1 ^= x0;
  x0 += x1; x1 = rotl32(x1,  6); x1 ^= x0;
  x0 += k2; x1 += k0 + 5u;
  o0 = x0; o1 = x1;
}

// ---------------------------------------------------------------------------
__global__ __launch_bounds__(256) void k_transpose(
    const float* __restrict__ w0, const float* __restrict__ w1,
    const float* __restrict__ w2, const float* __restrict__ w3,
    const float* __restrict__ w4, const float* __restrict__ w5,
    const float* __restrict__ w6, float* __restrict__ dst) {
  const float* src;
  switch (blockIdx.y) {
    case 0: src = w0; break;
    case 1: src = w1; break;
    case 2: src = w2; break;
    case 3: src = w3; break;
    case 4: src = w4; break;
    case 5: src = w5; break;
    default: src = w6; break;
  }
  int e = blockIdx.x;
  int h = threadIdx.x;
  dst[(size_t)blockIdx.y * 65536 + e * 256 + h] = src[h * 256 + e];
}

// ---------------------------------------------------------------------------
// Fused main kernel: 256 threads (thread = h channel), 32 rows per WG.
// Peak live VGPR state ~100 by design (per-tt fusion; l-outer ctx).
// ---------------------------------------------------------------------------
__global__ __launch_bounds__(256, 2) void k_main(
    const float* __restrict__ enc, const int* __restrict__ xes,
    const int* __restrict__ maskp, const float* __restrict__ wt,
    const float* __restrict__ b_in, const float* __restrict__ b_ctx,
    const float* __restrict__ V, float* __restrict__ att_out) {
  const int t = threadIdx.x;
  const int b0 = blockIdx.x * Rr;

  const float* WhT   = wt;
  const float* WvT   = wt + 65536;
  const float* WshT  = wt + 2 * 65536;
  const float* WsvT  = wt + 3 * 65536;
  const float* WeT   = wt + 4 * 65536;
  const float* WinT  = wt + 5 * 65536;
  const float* WctxT = wt + 6 * 65536;

  __shared__ int s_offh[5][Rr];
  __shared__ int s_offv[5][Rr];
  __shared__ int s_cond[5][Rr];
  __shared__ float xbuf[256 * XS];
  __shared__ float red[4][Rr];

  if (t < 5 * Rr) {
    int tt = t >> 5, r = t & 31;
    int base = ((b0 + r) * Tn + tt) * 3;
    s_offh[tt][r] = ((b0 + r) * Ln + xes[base]) * En;
    s_offv[tt][r] = ((b0 + r) * Ln + xes[base + 1]) * En;
    s_cond[tt][r] = (xes[base + 2] == 0) ? 1 : 0;
  }
  __syncthreads();

  float st[Rr];
#pragma unroll
  for (int r = 0; r < Rr; r++) st[r] = 0.f;

#pragma unroll 1
  for (int tt = 0; tt < 5; tt++) {
    // ---- stage 1: edge_tt[h=t][r] (x-operands via wave-uniform scalar loads)
    float acc[Rr];
#pragma unroll
    for (int r = 0; r < Rr; r++) acc[r] = 0.f;

#pragma unroll 1
    for (int e0 = 0; e0 < En; e0 += 4) {
      float wh[4], wv[4], wsh[4], wsv[4];
#pragma unroll
      for (int j = 0; j < 4; j++) {
        int o = (e0 + j) * 256 + t;
        wh[j] = WhT[o]; wv[j] = WvT[o]; wsh[j] = WshT[o]; wsv[j] = WsvT[o];
      }
#pragma unroll
      for (int r = 0; r < Rr; r++) {
        int oh = __builtin_amdgcn_readfirstlane(s_offh[tt][r]) + e0;
        int ov = __builtin_amdgcn_readfirstlane(s_offv[tt][r]) + e0;
        const float* __restrict__ ph = enc + oh;
        const float* __restrict__ pv = enc + ov;
        float a = acc[r];
        if (__builtin_amdgcn_readfirstlane(s_cond[tt][r])) {
#pragma unroll
          for (int j = 0; j < 4; j++) a += wh[j] * ph[j] + wv[j] * pv[j];
        } else {
#pragma unroll
          for (int j = 0; j < 4; j++) a += wsh[j] * ph[j] + wsv[j] * pv[j];
        }
        acc[r] = a;
      }
    }

    // ---- broadcast edge into xbuf[e=h][r]
    __syncthreads();   // prior xbuf readers done
#pragma unroll
    for (int q = 0; q < Rr / 4; q++) {
      float4 v4 = make_float4(acc[q * 4], acc[q * 4 + 1],
                              acc[q * 4 + 2], acc[q * 4 + 3]);
      *(float4*)&xbuf[t * XS + q * 4] = v4;
    }
    __syncthreads();

    // ---- stage 2: m = edge @ We^T, st = max(st, m)
    float m[Rr];
#pragma unroll
    for (int r = 0; r < Rr; r++) m[r] = 0.f;
#pragma unroll 1
    for (int e0 = 0; e0 < En; e0 += 4) {
      float w4[4];
#pragma unroll
      for (int j = 0; j < 4; j++) w4[j] = WeT[(e0 + j) * 256 + t];
#pragma unroll
      for (int j = 0; j < 4; j++) {
        const float* xb = &xbuf[(e0 + j) * XS];
#pragma unroll
        for (int q = 0; q < Rr / 4; q++) {
          float4 x = *(const float4*)(xb + q * 4);
          m[q * 4]     += w4[j] * x.x;
          m[q * 4 + 1] += w4[j] * x.y;
          m[q * 4 + 2] += w4[j] * x.z;
          m[q * 4 + 3] += w4[j] * x.w;
        }
      }
    }
#pragma unroll
    for (int r = 0; r < Rr; r++) st[r] = fmaxf(st[r], m[r]);
  }

  // ---- qt = relu(edge_4 + st); xbuf still holds edge_4 ------------------
  float inp[Rr];   // reuse as qt temporarily
#pragma unroll
  for (int r = 0; r < Rr; r++) inp[r] = fmaxf(xbuf[t * XS + r] + st[r], 0.f);
  __syncthreads();
#pragma unroll
  for (int q = 0; q < Rr / 4; q++) {
    float4 v4 = make_float4(inp[q * 4], inp[q * 4 + 1],
                            inp[q * 4 + 2], inp[q * 4 + 3]);
    *(float4*)&xbuf[t * XS + q * 4] = v4;
  }
  __syncthreads();

  // ---- inp = qt @ Win^T + b_in ------------------------------------------
#pragma unroll
  for (int r = 0; r < Rr; r++) inp[r] = 0.f;
#pragma unroll 1
  for (int e0 = 0; e0 < En; e0 += 4) {
    float w4[4];
#pragma unroll
    for (int j = 0; j < 4; j++) w4[j] = WinT[(e0 + j) * 256 + t];
#pragma unroll
    for (int j = 0; j < 4; j++) {
      const float* xb = &xbuf[(e0 + j) * XS];
#pragma unroll
      for (int q = 0; q < Rr / 4; q++) {
        float4 x = *(const float4*)(xb + q * 4);
        inp[q * 4]     += w4[j] * x.x;
        inp[q * 4 + 1] += w4[j] * x.y;
        inp[q * 4 + 2] += w4[j] * x.z;
        inp[q * 4 + 3] += w4[j] * x.w;
      }
    }
  }
  {
    float bi = b_in[t];
#pragma unroll
    for (int r = 0; r < Rr; r++) inp[r] += bi;
  }

  // ---- per-l: ctx then att reduction (l-outer keeps regs low) -----------
  const float Vt = V[t];
  const float bc = b_ctx[t];
  const int lane = t & 63, wid = t >> 6;

#pragma unroll 1
  for (int l = 0; l < Ln; l++) {
    float c[Rr];
#pragma unroll
    for (int r = 0; r < Rr; r++) c[r] = 0.f;
#pragma unroll 1
    for (int e0 = 0; e0 < En; e0 += 4) {
      float w4[4];
#pragma unroll
      for (int j = 0; j < 4; j++) w4[j] = WctxT[(e0 + j) * 256 + t];
#pragma unroll
      for (int r = 0; r < Rr; r++) {
        const float* __restrict__ px = enc + ((b0 + r) * Ln + l) * En + e0;
        float cc = c[r];
#pragma unroll
        for (int j = 0; j < 4; j++) cc += w4[j] * px[j];
        c[r] = cc;
      }
    }
#pragma unroll
    for (int r = 0; r < Rr; r++) c[r] = Vt * tanhf(inp[r] + bc + c[r]);
#pragma unroll
    for (int off = 32; off > 0; off >>= 1) {
#pragma unroll
      for (int r = 0; r < Rr; r++) c[r] += __shfl_down(c[r], off, 64);
    }
    if (lane == 0) {
#pragma unroll
      for (int r = 0; r < Rr; r++) red[wid][r] = c[r];
    }
    __syncthreads();
    if (t < Rr) {
      float a = red[0][t] + red[1][t] + red[2][t] + red[3][t];
      int b = b0 + t;
      if (!maskp[b * Ln + l]) a = NEGF;
      a = 10.f * tanhf(a);
      att_out[b * Ln + l] = a;
    }
    __syncthreads();
  }
}

// ---------------------------------------------------------------------------
// Column sums for softmax over axis 0 (fp64 accumulation), 1024 threads.
// ---------------------------------------------------------------------------
__global__ __launch_bounds__(1024) void k_colsum(const float* __restrict__ att,
                                                 float* __restrict__ sbuf) {
  int l = blockIdx.x;     // 0..6
  int t = threadIdx.x;
  double s = 0.0;
  for (int b = t; b < Bn; b += 1024) s += exp((double)att[b * Ln + l]);
  __shared__ double sd[1024];
  sd[t] = s;
  __syncthreads();
  for (int k = 512; k > 0; k >>= 1) {
    if (t < k) sd[t] += sd[t + k];
    __syncthreads();
  }
  if (t == 0) {
    sbuf[l] = (float)sd[0];
    sbuf[7 + l] = (float)log(sd[0]);
  }
}

// ---------------------------------------------------------------------------
// Gumbel-argmax sampling (threefry, partitionable bit-stream) + outputs.
// out = [idx(B) | p(B) | new_mask(B*7)] as float32.
// ---------------------------------------------------------------------------
__global__ __launch_bounds__(256) void k_sample(const float* __restrict__ att,
                                                const float* __restrict__ sbuf,
                                                const int* __restrict__ maskp,
                                                float* __restrict__ out) {
  int b = blockIdx.x * 256 + threadIdx.x;
  if (b >= Bn) return;
  float best = -3.0e38f;
  int bi = 0;
#pragma unroll
  for (int l = 0; l < Ln; l++) {
    uint32_t n = (uint32_t)(b * Ln + l);
    uint32_t o0, o1;
    threefry2x32(0u, 42u, 0u, n, o0, o1);
    uint32_t bits = o0 ^ o1;
    uint32_t fb = (bits >> 9) | 0x3f800000u;
    float f = __uint_as_float(fb) - 1.0f;
    float u = fmaxf(f, 1.1754943508222875e-38f);
    float g = -logf(-logf(u));
    float y = att[b * Ln + l] - sbuf[7 + l] + g;
    if (y > best) { best = y; bi = l; }
  }
  out[b] = (float)bi;
  out[Bn + b] = expf(att[b * Ln + bi] - sbuf[7 + bi]);
#pragma unroll
  for (int l = 0; l < Ln; l++)
    out[2 * Bn + b * Ln + l] = (float)(maskp[b * Ln + l] - ((l == bi) ? 1 : 0));
}

// ---------------------------------------------------------------------------
extern "C" void kernel_launch(void* const* d_in, const int* in_sizes, int n_in,
                              void* d_out, int out_size, void* d_ws,
                              size_t ws_size, hipStream_t stream) {
  const float* enc   = (const float*)d_in[0];
  const int*   xes   = (const int*)d_in[1];
  const int*   maskp = (const int*)d_in[2];
  const float* W_h   = (const float*)d_in[3];
  const float* W_v   = (const float*)d_in[4];
  const float* Ws_h  = (const float*)d_in[5];
  const float* Ws_v  = (const float*)d_in[6];
  const float* W_e   = (const float*)d_in[7];
  const float* W_in  = (const float*)d_in[8];
  const float* b_in  = (const float*)d_in[9];
  const float* W_ctx = (const float*)d_in[10];
  const float* b_ctx = (const float*)d_in[11];
  const float* V     = (const float*)d_in[12];

  float* ws   = (float*)d_ws;
  float* wt   = ws;                   // 7*65536 floats
  float* att  = ws + 7 * 65536;       // B*7 floats
  float* sbuf = att + Bn * Ln;        // 14 floats

  dim3 gT(256, 7);
  k_transpose<<<gT, 256, 0, stream>>>(W_h, W_v, Ws_h, Ws_v, W_e, W_in, W_ctx, wt);
  k_main<<<Bn / Rr, 256, 0, stream>>>(enc, xes, maskp, wt, b_in, b_ctx, V, att);
  k_colsum<<<7, 1024, 0, stream>>>(att, sbuf);
  k_sample<<<Bn / 256, 256, 0, stream>>>(att, sbuf, maskp, (float*)d_out);
}

// Round 3
// 17245.480 us; speedup vs baseline: 1.0870x; 1.0870x over previous
//
#include <hip/hip_runtime.h>
#include <stdint.h>
#include <math.h>

#define Bn 32768
#define Ln 7
#define Tn 6
#define En 256
#define Rr 8
#define NEGF (-1000000000.0f)

// ---------------------------------------------------------------------------
// ws layout (floats):
//   [0, 7*65536)   : 7 transposed weights WT[m][e][h]: Wh,Wv,Wsh,Wsv,We,Win,Wctx
//   [458752, +B*7) : att[b][l]
//   then 14 floats : S[7], logS[7]
// ---------------------------------------------------------------------------

__device__ __forceinline__ uint32_t rotl32(uint32_t x, int d) {
  return (x << d) | (x >> (32 - d));
}

// JAX threefry2x32, 20 rounds (matches jax/_src/prng.py)
__device__ __forceinline__ void threefry2x32(uint32_t k0, uint32_t k1,
                                             uint32_t x0, uint32_t x1,
                                             uint32_t& o0, uint32_t& o1) {
  uint32_t k2 = k0 ^ k1 ^ 0x1BD11BDAu;
  x0 += k0; x1 += k1;
  x0 += x1; x1 = rotl32(x1, 13); x1 ^= x0;
  x0 += x1; x1 = rotl32(x1, 15); x1 ^= x0;
  x0 += x1; x1 = rotl32(x1, 26); x1 ^= x0;
  x0 += x1; x1 = rotl32(x1,  6); x1 ^= x0;
  x0 += k1; x1 += k2 + 1u;
  x0 += x1; x1 = rotl32(x1, 17); x1 ^= x0;
  x0 += x1; x1 = rotl32(x1, 29); x1 ^= x0;
  x0 += x1; x1 = rotl32(x1, 16); x1 ^= x0;
  x0 += x1; x1 = rotl32(x1, 24); x1 ^= x0;
  x0 += k2; x1 += k0 + 2u;
  x0 += x1; x1 = rotl32(x1, 13); x1 ^= x0;
  x0 += x1; x1 = rotl32(x1, 15); x1 ^= x0;
  x0 += x1; x1 = rotl32(x1, 26); x1 ^= x0;
  x0 += x1; x1 = rotl32(x1,  6); x1 ^= x0;
  x0 += k0; x1 += k1 + 3u;
  x0 += x1; x1 = rotl32(x1, 17); x1 ^= x0;
  x0 += x1; x1 = rotl32(x1, 29); x1 ^= x0;
  x0 += x1; x1 = rotl32(x1, 16); x1 ^= x0;
  x0 += x1; x1 = rotl32(x1, 24); x1 ^= x0;
  x0 += k1; x1 += k2 + 4u;
  x0 += x1; x1 = rotl32(x1, 13); x1 ^= x0;
  x0 += x1; x1 = rotl32(x1, 15); x1 ^= x0;
  x0 += x1; x1 = rotl32(x1, 26); x1 ^= x0;
  x0 += x1; x1 = rotl32(x1,  6); x1 ^= x0;
  x0 += k2; x1 += k0 + 5u;
  o0 = x0; o1 = x1;
}

// ---------------------------------------------------------------------------
__global__ __launch_bounds__(256) void k_transpose(
    const float* __restrict__ w0, const float* __restrict__ w1,
    const float* __restrict__ w2, const float* __restrict__ w3,
    const float* __restrict__ w4, const float* __restrict__ w5,
    const float* __restrict__ w6, float* __restrict__ dst) {
  const float* src;
  switch (blockIdx.y) {
    case 0: src = w0; break;
    case 1: src = w1; break;
    case 2: src = w2; break;
    case 3: src = w3; break;
    case 4: src = w4; break;
    case 5: src = w5; break;
    default: src = w6; break;
  }
  int e = blockIdx.x;
  int h = threadIdx.x;
  dst[(size_t)blockIdx.y * 65536 + e * 256 + h] = src[h * 256 + e];
}

// ---------------------------------------------------------------------------
// Fused main kernel: 256 threads (thread = h channel), 8 rows per WG.
// All x-operands served from a 56 KB LDS stage of the block's enc rows.
// Peak live VGPR state ~85 by design; no launch_bounds occupancy hint.
// ---------------------------------------------------------------------------
__global__ __launch_bounds__(256) void k_main(
    const float* __restrict__ enc, const int* __restrict__ xes,
    const int* __restrict__ maskp, const float* __restrict__ wt,
    const float* __restrict__ b_in, const float* __restrict__ b_ctx,
    const float* __restrict__ V, float* __restrict__ att_out) {
  const int t = threadIdx.x;
  const int b0 = blockIdx.x * Rr;

  const float* WhT   = wt;
  const float* WvT   = wt + 65536;
  const float* WshT  = wt + 2 * 65536;
  const float* WsvT  = wt + 3 * 65536;
  const float* WeT   = wt + 4 * 65536;
  const float* WinT  = wt + 5 * 65536;
  const float* WctxT = wt + 6 * 65536;

  __shared__ float erow[Rr * Ln * En];   // 56 KB: all enc rows of this block
  __shared__ float xbuf[256 * Rr];       // 8 KB: per-tt edge broadcast
  __shared__ float red[4][Rr];

  // ---- stage 0: coalesced load of 56 contiguous enc rows into LDS -------
  {
    const float4* enc4 = (const float4*)(enc + (size_t)b0 * Ln * En);
    float4* er4 = (float4*)erow;
#pragma unroll
    for (int i = 0; i < (Rr * Ln * En) / (4 * 256); i++)   // 14 iters
      er4[i * 256 + t] = enc4[i * 256 + t];
  }

  // ---- per-wave packed gather offsets in 2 VGPRs ------------------------
  // lane i<40 of each wave holds pair (tt=i>>3, r=i&7):
  //   voh = (r*7+h)*256 | (cond?sign:0), vov = (r*7+v)*256
  int voh = 0, vov = 0;
  {
    int i = t & 63;
    if (i < 5 * Rr) {
      int tt = i >> 3, r = i & 7;
      int base = ((b0 + r) * Tn + tt) * 3;
      int h = xes[base], v = xes[base + 1], c = xes[base + 2];
      voh = ((r * Ln + h) << 8) | (c == 0 ? (int)0x80000000 : 0);
      vov = (r * Ln + v) << 8;
    }
  }
  __syncthreads();

  // ---- stage 1: edges, single pass over the 4 edge-weight matrices ------
  float acc[5][Rr];
#pragma unroll
  for (int i = 0; i < 5; i++)
#pragma unroll
    for (int r = 0; r < Rr; r++) acc[i][r] = 0.f;

#pragma unroll 1
  for (int e0 = 0; e0 < En; e0 += 4) {
    float wh[4], wv[4], wsh[4], wsv[4];
#pragma unroll
    for (int j = 0; j < 4; j++) {
      int o = (e0 + j) * 256 + t;
      wh[j] = WhT[o]; wv[j] = WvT[o]; wsh[j] = WshT[o]; wsv[j] = WsvT[o];
    }
#pragma unroll
    for (int tt = 0; tt < 5; tt++) {
#pragma unroll
      for (int r = 0; r < Rr; r++) {
        int oh = __builtin_amdgcn_readlane(voh, tt * Rr + r);
        int ov = __builtin_amdgcn_readlane(vov, tt * Rr + r);
        float4 xh = *(const float4*)(erow + (oh & 0x7fffffff) + e0);
        float4 xv = *(const float4*)(erow + ov + e0);
        float a = acc[tt][r];
        if (oh < 0) {
          a += wh[0] * xh.x + wh[1] * xh.y + wh[2] * xh.z + wh[3] * xh.w;
          a += wv[0] * xv.x + wv[1] * xv.y + wv[2] * xv.z + wv[3] * xv.w;
        } else {
          a += wsh[0] * xh.x + wsh[1] * xh.y + wsh[2] * xh.z + wsh[3] * xh.w;
          a += wsv[0] * xv.x + wsv[1] * xv.y + wsv[2] * xv.z + wsv[3] * xv.w;
        }
        acc[tt][r] = a;
      }
    }
  }

  // ---- stage 2: m_tt = edge_tt @ We^T, st = max(0, m_0..m_4) ------------
  float st[Rr];
#pragma unroll
  for (int r = 0; r < Rr; r++) st[r] = 0.f;

#pragma unroll 1
  for (int tt = 0; tt < 5; tt++) {
    __syncthreads();
    *(float4*)&xbuf[t * Rr]     = make_float4(acc[tt][0], acc[tt][1],
                                              acc[tt][2], acc[tt][3]);
    *(float4*)&xbuf[t * Rr + 4] = make_float4(acc[tt][4], acc[tt][5],
                                              acc[tt][6], acc[tt][7]);
    __syncthreads();
    float m[Rr];
#pragma unroll
    for (int r = 0; r < Rr; r++) m[r] = 0.f;
#pragma unroll 1
    for (int e0 = 0; e0 < En; e0 += 4) {
      float w4[4];
#pragma unroll
      for (int j = 0; j < 4; j++) w4[j] = WeT[(e0 + j) * 256 + t];
#pragma unroll
      for (int j = 0; j < 4; j++) {
        const float* xb = &xbuf[(e0 + j) * Rr];
        float4 x0 = *(const float4*)xb;
        float4 x1 = *(const float4*)(xb + 4);
        m[0] += w4[j] * x0.x; m[1] += w4[j] * x0.y;
        m[2] += w4[j] * x0.z; m[3] += w4[j] * x0.w;
        m[4] += w4[j] * x1.x; m[5] += w4[j] * x1.y;
        m[6] += w4[j] * x1.z; m[7] += w4[j] * x1.w;
      }
    }
#pragma unroll
    for (int r = 0; r < Rr; r++) st[r] = fmaxf(st[r], m[r]);
  }

  // ---- qt = relu(edge_4 + st) ------------------------------------------
  float q[Rr];
#pragma unroll
  for (int r = 0; r < Rr; r++) q[r] = fmaxf(acc[4][r] + st[r], 0.f);
  __syncthreads();
  *(float4*)&xbuf[t * Rr]     = make_float4(q[0], q[1], q[2], q[3]);
  *(float4*)&xbuf[t * Rr + 4] = make_float4(q[4], q[5], q[6], q[7]);
  __syncthreads();

  // ---- inp = qt @ Win^T + b_in -----------------------------------------
  float inp[Rr];
#pragma unroll
  for (int r = 0; r < Rr; r++) inp[r] = 0.f;
#pragma unroll 1
  for (int e0 = 0; e0 < En; e0 += 4) {
    float w4[4];
#pragma unroll
    for (int j = 0; j < 4; j++) w4[j] = WinT[(e0 + j) * 256 + t];
#pragma unroll
    for (int j = 0; j < 4; j++) {
      const float* xb = &xbuf[(e0 + j) * Rr];
      float4 x0 = *(const float4*)xb;
      float4 x1 = *(const float4*)(xb + 4);
      inp[0] += w4[j] * x0.x; inp[1] += w4[j] * x0.y;
      inp[2] += w4[j] * x0.z; inp[3] += w4[j] * x0.w;
      inp[4] += w4[j] * x1.x; inp[5] += w4[j] * x1.y;
      inp[6] += w4[j] * x1.z; inp[7] += w4[j] * x1.w;
    }
  }
  {
    float bi = b_in[t];
#pragma unroll
    for (int r = 0; r < Rr; r++) inp[r] += bi;
  }

  // ---- ctx[l][r]: x from erow broadcasts, single Wctx pass --------------
  float c[Ln][Rr];
#pragma unroll
  for (int l = 0; l < Ln; l++)
#pragma unroll
    for (int r = 0; r < Rr; r++) c[l][r] = 0.f;

#pragma unroll 1
  for (int e0 = 0; e0 < En; e0 += 4) {
    float w4[4];
#pragma unroll
    for (int j = 0; j < 4; j++) w4[j] = WctxT[(e0 + j) * 256 + t];
#pragma unroll
    for (int l = 0; l < Ln; l++) {
#pragma unroll
      for (int r = 0; r < Rr; r++) {
        float4 x = *(const float4*)(erow + (r * Ln + l) * En + e0);
        c[l][r] += w4[0] * x.x + w4[1] * x.y + w4[2] * x.z + w4[3] * x.w;
      }
    }
  }

  // ---- att[b,l] reduction ----------------------------------------------
  const float Vt = V[t];
  const float bc = b_ctx[t];
  const int lane = t & 63, wid = t >> 6;

#pragma unroll 1
  for (int l = 0; l < Ln; l++) {
    float v[Rr];
#pragma unroll
    for (int r = 0; r < Rr; r++) v[r] = Vt * tanhf(inp[r] + bc + c[l][r]);
#pragma unroll
    for (int off = 32; off > 0; off >>= 1) {
#pragma unroll
      for (int r = 0; r < Rr; r++) v[r] += __shfl_down(v[r], off, 64);
    }
    if (lane == 0) {
#pragma unroll
      for (int r = 0; r < Rr; r++) red[wid][r] = v[r];
    }
    __syncthreads();
    if (t < Rr) {
      float a = red[0][t] + red[1][t] + red[2][t] + red[3][t];
      int b = b0 + t;
      if (!maskp[b * Ln + l]) a = NEGF;
      a = 10.f * tanhf(a);
      att_out[b * Ln + l] = a;
    }
    __syncthreads();
  }
}

// ---------------------------------------------------------------------------
__global__ __launch_bounds__(1024) void k_colsum(const float* __restrict__ att,
                                                 float* __restrict__ sbuf) {
  int l = blockIdx.x;     // 0..6
  int t = threadIdx.x;
  double s = 0.0;
  for (int b = t; b < Bn; b += 1024) s += exp((double)att[b * Ln + l]);
  __shared__ double sd[1024];
  sd[t] = s;
  __syncthreads();
  for (int k = 512; k > 0; k >>= 1) {
    if (t < k) sd[t] += sd[t + k];
    __syncthreads();
  }
  if (t == 0) {
    sbuf[l] = (float)sd[0];
    sbuf[7 + l] = (float)log(sd[0]);
  }
}

// ---------------------------------------------------------------------------
__global__ __launch_bounds__(256) void k_sample(const float* __restrict__ att,
                                                const float* __restrict__ sbuf,
                                                const int* __restrict__ maskp,
                                                float* __restrict__ out) {
  int b = blockIdx.x * 256 + threadIdx.x;
  if (b >= Bn) return;
  float best = -3.0e38f;
  int bi = 0;
#pragma unroll
  for (int l = 0; l < Ln; l++) {
    uint32_t n = (uint32_t)(b * Ln + l);
    uint32_t o0, o1;
    threefry2x32(0u, 42u, 0u, n, o0, o1);
    uint32_t bits = o0 ^ o1;
    uint32_t fb = (bits >> 9) | 0x3f800000u;
    float f = __uint_as_float(fb) - 1.0f;
    float u = fmaxf(f, 1.1754943508222875e-38f);
    float g = -logf(-logf(u));
    float y = att[b * Ln + l] - sbuf[7 + l] + g;
    if (y > best) { best = y; bi = l; }
  }
  out[b] = (float)bi;
  out[Bn + b] = expf(att[b * Ln + bi] - sbuf[7 + bi]);
#pragma unroll
  for (int l = 0; l < Ln; l++)
    out[2 * Bn + b * Ln + l] = (float)(maskp[b * Ln + l] - ((l == bi) ? 1 : 0));
}

// ---------------------------------------------------------------------------
extern "C" void kernel_launch(void* const* d_in, const int* in_sizes, int n_in,
                              void* d_out, int out_size, void* d_ws,
                              size_t ws_size, hipStream_t stream) {
  const float* enc   = (const float*)d_in[0];
  const int*   xes   = (const int*)d_in[1];
  const int*   maskp = (const int*)d_in[2];
  const float* W_h   = (const float*)d_in[3];
  const float* W_v   = (const float*)d_in[4];
  const float* Ws_h  = (const float*)d_in[5];
  const float* Ws_v  = (const float*)d_in[6];
  const float* W_e   = (const float*)d_in[7];
  const float* W_in  = (const float*)d_in[8];
  const float* b_in  = (const float*)d_in[9];
  const float* W_ctx = (const float*)d_in[10];
  const float* b_ctx = (const float*)d_in[11];
  const float* V     = (const float*)d_in[12];

  float* ws   = (float*)d_ws;
  float* wt   = ws;                   // 7*65536 floats
  float* att  = ws + 7 * 65536;       // B*7 floats
  float* sbuf = att + Bn * Ln;        // 14 floats

  dim3 gT(256, 7);
  k_transpose<<<gT, 256, 0, stream>>>(W_h, W_v, Ws_h, Ws_v, W_e, W_in, W_ctx, wt);
  k_main<<<Bn / Rr, 256, 0, stream>>>(enc, xes, maskp, wt, b_in, b_ctx, V, att);
  k_colsum<<<7, 1024, 0, stream>>>(att, sbuf);
  k_sample<<<Bn / 256, 256, 0, stream>>>(att, sbuf, maskp, (float*)d_out);
}

// Round 4
// 13278.563 us; speedup vs baseline: 1.4117x; 1.2987x over previous
//
#include <hip/hip_runtime.h>
#include <stdint.h>
#include <math.h>

#define Bn 32768
#define Ln 7
#define Tn 6
#define En 256
#define Rr 8
#define NEGF (-1000000000.0f)

// ---------------------------------------------------------------------------
// ws layout (floats):
//   [0, 7*65536)   : 7 BLOCKED weights WB[m][(e>>3)*256+h][8] order:
//                    Wh,Wv,Wsh,Wsv,We,Win,Wctx
//   [458752, +B*7) : att[b][l]
//   then 14 floats : S[7], logS[7]
// ---------------------------------------------------------------------------

__device__ __forceinline__ uint32_t rotl32(uint32_t x, int d) {
  return (x << d) | (x >> (32 - d));
}

// JAX threefry2x32, 20 rounds
__device__ __forceinline__ void threefry2x32(uint32_t k0, uint32_t k1,
                                             uint32_t x0, uint32_t x1,
                                             uint32_t& o0, uint32_t& o1) {
  uint32_t k2 = k0 ^ k1 ^ 0x1BD11BDAu;
  x0 += k0; x1 += k1;
  x0 += x1; x1 = rotl32(x1, 13); x1 ^= x0;
  x0 += x1; x1 = rotl32(x1, 15); x1 ^= x0;
  x0 += x1; x1 = rotl32(x1, 26); x1 ^= x0;
  x0 += x1; x1 = rotl32(x1,  6); x1 ^= x0;
  x0 += k1; x1 += k2 + 1u;
  x0 += x1; x1 = rotl32(x1, 17); x1 ^= x0;
  x0 += x1; x1 = rotl32(x1, 29); x1 ^= x0;
  x0 += x1; x1 = rotl32(x1, 16); x1 ^= x0;
  x0 += x1; x1 = rotl32(x1, 24); x1 ^= x0;
  x0 += k2; x1 += k0 + 2u;
  x0 += x1; x1 = rotl32(x1, 13); x1 ^= x0;
  x0 += x1; x1 = rotl32(x1, 15); x1 ^= x0;
  x0 += x1; x1 = rotl32(x1, 26); x1 ^= x0;
  x0 += x1; x1 = rotl32(x1,  6); x1 ^= x0;
  x0 += k0; x1 += k1 + 3u;
  x0 += x1; x1 = rotl32(x1, 17); x1 ^= x0;
  x0 += x1; x1 = rotl32(x1, 29); x1 ^= x0;
  x0 += x1; x1 = rotl32(x1, 16); x1 ^= x0;
  x0 += x1; x1 = rotl32(x1, 24); x1 ^= x0;
  x0 += k1; x1 += k2 + 4u;
  x0 += x1; x1 = rotl32(x1, 13); x1 ^= x0;
  x0 += x1; x1 = rotl32(x1, 15); x1 ^= x0;
  x0 += x1; x1 = rotl32(x1, 26); x1 ^= x0;
  x0 += x1; x1 = rotl32(x1,  6); x1 ^= x0;
  x0 += k2; x1 += k0 + 5u;
  o0 = x0; o1 = x1;
}

// ---------------------------------------------------------------------------
// Blocked-transpose weights: WB[(e>>3)*256 + h][j= e&7] = W[h][e]
// ---------------------------------------------------------------------------
__global__ __launch_bounds__(256) void k_prep(
    const float* __restrict__ w0, const float* __restrict__ w1,
    const float* __restrict__ w2, const float* __restrict__ w3,
    const float* __restrict__ w4, const float* __restrict__ w5,
    const float* __restrict__ w6, float* __restrict__ dst) {
  const float* src;
  switch (blockIdx.y) {
    case 0: src = w0; break;
    case 1: src = w1; break;
    case 2: src = w2; break;
    case 3: src = w3; break;
    case 4: src = w4; break;
    case 5: src = w5; break;
    default: src = w6; break;
  }
  int e = blockIdx.x;       // 0..255
  int h = threadIdx.x;      // 0..255
  dst[blockIdx.y * 65536 + (((e >> 3) * 256 + h) << 3) + (e & 7)] =
      src[h * 256 + e];
}

// ---------------------------------------------------------------------------
// Shared matvec helper: m = xbuf(8 rows broadcast) @ WB-column(t), K=256.
// ---------------------------------------------------------------------------
#define MJ(WJ, J) {                                                      \
    const float4 xb0 = *(const float4*)(xbuf + ((e0 + J) << 3));         \
    const float4 xb1 = *(const float4*)(xbuf + ((e0 + J) << 3) + 4);     \
    m0.x += (WJ) * xb0.x; m0.y += (WJ) * xb0.y;                          \
    m0.z += (WJ) * xb0.z; m0.w += (WJ) * xb0.w;                          \
    m1.x += (WJ) * xb1.x; m1.y += (WJ) * xb1.y;                          \
    m1.z += (WJ) * xb1.z; m1.w += (WJ) * xb1.w; }

__device__ __forceinline__ void matv8(const float* __restrict__ WB,
                                      const float* xbuf, int t,
                                      float4& m0, float4& m1) {
  m0 = make_float4(0.f, 0.f, 0.f, 0.f);
  m1 = make_float4(0.f, 0.f, 0.f, 0.f);
#pragma unroll 1
  for (int e0 = 0; e0 < En; e0 += 8) {
    const float* wp = WB + e0 * 256 + t * 8;
    const float4 w0 = *(const float4*)wp;
    const float4 w1 = *(const float4*)(wp + 4);
    MJ(w0.x, 0) MJ(w0.y, 1) MJ(w0.z, 2) MJ(w0.w, 3)
    MJ(w1.x, 4) MJ(w1.y, 5) MJ(w1.z, 6) MJ(w1.w, 7)
  }
}

// ---------------------------------------------------------------------------
// Main fused kernel. 256 threads (thread = h), 8 rows per WG.
// x-operands via wave-uniform global loads; no private arrays.
// ---------------------------------------------------------------------------
__global__ __launch_bounds__(256) void k_main(
    const float* __restrict__ enc, const int* __restrict__ xes,
    const int* __restrict__ maskp, const float* __restrict__ wt,
    const float* __restrict__ b_in, const float* __restrict__ b_ctx,
    const float* __restrict__ V, float* __restrict__ att_out) {
  const int t = threadIdx.x;
  const int b0 = blockIdx.x * Rr;

  const float* WhB   = wt;
  const float* WvB   = wt + 65536;
  const float* WshB  = wt + 2 * 65536;
  const float* WsvB  = wt + 3 * 65536;
  const float* WeB   = wt + 4 * 65536;
  const float* WinB  = wt + 5 * 65536;
  const float* WctxB = wt + 6 * 65536;

  __shared__ float xbuf[256 * 8];   // 8 KB broadcast buffer
  __shared__ float red[4][Rr];

  const char* encB = (const char*)enc + (size_t)b0 * (Ln * En * 4);

  // ---- pack per-pair byte offsets (relative to encB) + cond mask --------
  // lane p<40: pair (tt=p>>3, r=p&7): pk = relH | relV<<16 (each <=57344)
  unsigned int pk = 0;
  bool condp = false;
  {
    int p = t & 63;
    if (p < 40) {
      int tt = p >> 3, r = p & 7;
      int base = ((b0 + r) * Tn + tt) * 3;
      int h = xes[base], v = xes[base + 1];
      condp = (xes[base + 2] == 0);
      pk = (unsigned)((r * Ln + h) << 10) | ((unsigned)((r * Ln + v) << 10) << 16);
    }
  }
  const unsigned long long cmask = __ballot(condp);

#define DSK(p) const int sk##p = __builtin_amdgcn_readlane((int)pk, p);
  DSK(0) DSK(1) DSK(2) DSK(3) DSK(4) DSK(5) DSK(6) DSK(7)
  DSK(8) DSK(9) DSK(10) DSK(11) DSK(12) DSK(13) DSK(14) DSK(15)
  DSK(16) DSK(17) DSK(18) DSK(19) DSK(20) DSK(21) DSK(22) DSK(23)
  DSK(24) DSK(25) DSK(26) DSK(27) DSK(28) DSK(29) DSK(30) DSK(31)
  DSK(32) DSK(33) DSK(34) DSK(35) DSK(36) DSK(37) DSK(38) DSK(39)

  // ---- stage 1: 40 edge accumulators as named float4s -------------------
  float4 a00 = make_float4(0,0,0,0), a01 = make_float4(0,0,0,0);
  float4 a10 = make_float4(0,0,0,0), a11 = make_float4(0,0,0,0);
  float4 a20 = make_float4(0,0,0,0), a21 = make_float4(0,0,0,0);
  float4 a30 = make_float4(0,0,0,0), a31 = make_float4(0,0,0,0);
  float4 a40 = make_float4(0,0,0,0), a41 = make_float4(0,0,0,0);

#define ST1(p, AV, C) {                                                       \
    const int oh_ = ve + (sk##p & 0xffff);                                    \
    const int ov_ = ve + (int)(((unsigned)sk##p) >> 16);                      \
    const float4 xh0 = *(const float4*)(encB + oh_);                          \
    const float4 xh1 = *(const float4*)(encB + oh_ + 16);                     \
    const float4 xv0 = *(const float4*)(encB + ov_);                          \
    const float4 xv1 = *(const float4*)(encB + ov_ + 16);                     \
    if (cmask & (1ull << p)) {                                                \
      AV.C += wh0.x*xh0.x + wh0.y*xh0.y + wh0.z*xh0.z + wh0.w*xh0.w           \
            + wh1.x*xh1.x + wh1.y*xh1.y + wh1.z*xh1.z + wh1.w*xh1.w           \
            + wv0.x*xv0.x + wv0.y*xv0.y + wv0.z*xv0.z + wv0.w*xv0.w           \
            + wv1.x*xv1.x + wv1.y*xv1.y + wv1.z*xv1.z + wv1.w*xv1.w;          \
    } else {                                                                  \
      AV.C += wsh0.x*xh0.x + wsh0.y*xh0.y + wsh0.z*xh0.z + wsh0.w*xh0.w       \
            + wsh1.x*xh1.x + wsh1.y*xh1.y + wsh1.z*xh1.z + wsh1.w*xh1.w       \
            + wsv0.x*xv0.x + wsv0.y*xv0.y + wsv0.z*xv0.z + wsv0.w*xv0.w       \
            + wsv1.x*xv1.x + wsv1.y*xv1.y + wsv1.z*xv1.z + wsv1.w*xv1.w;      \
    } }
#define FENCE __builtin_amdgcn_sched_barrier(0);

#pragma unroll 1
  for (int e0 = 0; e0 < En; e0 += 8) {
    const int ve = e0 * 4;                    // byte offset within a row
    const float* whp  = WhB  + e0 * 256 + t * 8;
    const float* wvp  = WvB  + e0 * 256 + t * 8;
    const float* wshp = WshB + e0 * 256 + t * 8;
    const float* wsvp = WsvB + e0 * 256 + t * 8;
    const float4 wh0  = *(const float4*)whp,  wh1  = *(const float4*)(whp + 4);
    const float4 wv0  = *(const float4*)wvp,  wv1  = *(const float4*)(wvp + 4);
    const float4 wsh0 = *(const float4*)wshp, wsh1 = *(const float4*)(wshp + 4);
    const float4 wsv0 = *(const float4*)wsvp, wsv1 = *(const float4*)(wsvp + 4);
    ST1(0,a00,x)  ST1(1,a00,y)  ST1(2,a00,z)  ST1(3,a00,w)  FENCE
    ST1(4,a01,x)  ST1(5,a01,y)  ST1(6,a01,z)  ST1(7,a01,w)  FENCE
    ST1(8,a10,x)  ST1(9,a10,y)  ST1(10,a10,z) ST1(11,a10,w) FENCE
    ST1(12,a11,x) ST1(13,a11,y) ST1(14,a11,z) ST1(15,a11,w) FENCE
    ST1(16,a20,x) ST1(17,a20,y) ST1(18,a20,z) ST1(19,a20,w) FENCE
    ST1(20,a21,x) ST1(21,a21,y) ST1(22,a21,z) ST1(23,a21,w) FENCE
    ST1(24,a30,x) ST1(25,a30,y) ST1(26,a30,z) ST1(27,a30,w) FENCE
    ST1(28,a31,x) ST1(29,a31,y) ST1(30,a31,z) ST1(31,a31,w) FENCE
    ST1(32,a40,x) ST1(33,a40,y) ST1(34,a40,z) ST1(35,a40,w) FENCE
    ST1(36,a41,x) ST1(37,a41,y) ST1(38,a41,z) ST1(39,a41,w) FENCE
  }

  // ---- stage 2: st = max over tt of edge_tt @ We^T ----------------------
  float4 st0 = make_float4(0,0,0,0), st1 = make_float4(0,0,0,0);
#define ST2(AVL, AVH) {                                                  \
    __syncthreads();                                                     \
    *(float4*)(xbuf + t * 8)     = AVL;                                  \
    *(float4*)(xbuf + t * 8 + 4) = AVH;                                  \
    __syncthreads();                                                     \
    float4 m0, m1;                                                       \
    matv8(WeB, xbuf, t, m0, m1);                                         \
    st0.x = fmaxf(st0.x, m0.x); st0.y = fmaxf(st0.y, m0.y);              \
    st0.z = fmaxf(st0.z, m0.z); st0.w = fmaxf(st0.w, m0.w);              \
    st1.x = fmaxf(st1.x, m1.x); st1.y = fmaxf(st1.y, m1.y);              \
    st1.z = fmaxf(st1.z, m1.z); st1.w = fmaxf(st1.w, m1.w); }
  ST2(a00, a01) ST2(a10, a11) ST2(a20, a21) ST2(a30, a31) ST2(a40, a41)

  // ---- qt = relu(edge_4 + st); broadcast; inp = qt @ Win^T + b_in -------
  float4 q0, q1;
  q0.x = fmaxf(a40.x + st0.x, 0.f); q0.y = fmaxf(a40.y + st0.y, 0.f);
  q0.z = fmaxf(a40.z + st0.z, 0.f); q0.w = fmaxf(a40.w + st0.w, 0.f);
  q1.x = fmaxf(a41.x + st1.x, 0.f); q1.y = fmaxf(a41.y + st1.y, 0.f);
  q1.z = fmaxf(a41.z + st1.z, 0.f); q1.w = fmaxf(a41.w + st1.w, 0.f);
  __syncthreads();
  *(float4*)(xbuf + t * 8)     = q0;
  *(float4*)(xbuf + t * 8 + 4) = q1;
  __syncthreads();
  float4 i0, i1;
  matv8(WinB, xbuf, t, i0, i1);
  {
    const float bi = b_in[t];
    i0.x += bi; i0.y += bi; i0.z += bi; i0.w += bi;
    i1.x += bi; i1.y += bi; i1.z += bi; i1.w += bi;
  }

  // ---- ctx: 56 accumulators as named float4s ----------------------------
  float4 c00 = make_float4(0,0,0,0), c01 = make_float4(0,0,0,0);
  float4 c10 = make_float4(0,0,0,0), c11 = make_float4(0,0,0,0);
  float4 c20 = make_float4(0,0,0,0), c21 = make_float4(0,0,0,0);
  float4 c30 = make_float4(0,0,0,0), c31 = make_float4(0,0,0,0);
  float4 c40 = make_float4(0,0,0,0), c41 = make_float4(0,0,0,0);
  float4 c50 = make_float4(0,0,0,0), c51 = make_float4(0,0,0,0);
  float4 c60 = make_float4(0,0,0,0), c61 = make_float4(0,0,0,0);

#define CTXR(RL, CV, C) {                                                \
    const float4 x0 = *(const float4*)(encB + ve + (RL) * 1024);         \
    const float4 x1 = *(const float4*)(encB + ve + (RL) * 1024 + 16);    \
    CV.C += w0.x*x0.x + w0.y*x0.y + w0.z*x0.z + w0.w*x0.w                \
          + w1.x*x1.x + w1.y*x1.y + w1.z*x1.z + w1.w*x1.w; }

#pragma unroll 1
  for (int e0 = 0; e0 < En; e0 += 8) {
    const int ve = e0 * 4;
    const float* wp = WctxB + e0 * 256 + t * 8;
    const float4 w0 = *(const float4*)wp;
    const float4 w1 = *(const float4*)(wp + 4);
    CTXR(0,c00,x)  CTXR(7,c00,y)  CTXR(14,c00,z) CTXR(21,c00,w) FENCE
    CTXR(28,c01,x) CTXR(35,c01,y) CTXR(42,c01,z) CTXR(49,c01,w) FENCE
    CTXR(1,c10,x)  CTXR(8,c10,y)  CTXR(15,c10,z) CTXR(22,c10,w) FENCE
    CTXR(29,c11,x) CTXR(36,c11,y) CTXR(43,c11,z) CTXR(50,c11,w) FENCE
    CTXR(2,c20,x)  CTXR(9,c20,y)  CTXR(16,c20,z) CTXR(23,c20,w) FENCE
    CTXR(30,c21,x) CTXR(37,c21,y) CTXR(44,c21,z) CTXR(51,c21,w) FENCE
    CTXR(3,c30,x)  CTXR(10,c30,y) CTXR(17,c30,z) CTXR(24,c30,w) FENCE
    CTXR(31,c31,x) CTXR(38,c31,y) CTXR(45,c31,z) CTXR(52,c31,w) FENCE
    CTXR(4,c40,x)  CTXR(11,c40,y) CTXR(18,c40,z) CTXR(25,c40,w) FENCE
    CTXR(32,c41,x) CTXR(39,c41,y) CTXR(46,c41,z) CTXR(53,c41,w) FENCE
    CTXR(5,c50,x)  CTXR(12,c50,y) CTXR(19,c50,z) CTXR(26,c50,w) FENCE
    CTXR(33,c51,x) CTXR(40,c51,y) CTXR(47,c51,z) CTXR(54,c51,w) FENCE
    CTXR(6,c60,x)  CTXR(13,c60,y) CTXR(20,c60,z) CTXR(27,c60,w) FENCE
    CTXR(34,c61,x) CTXR(41,c61,y) CTXR(48,c61,z) CTXR(55,c61,w) FENCE
  }

  // ---- att reduction per l ---------------------------------------------
  const float Vt = V[t];
  const float bc = b_ctx[t];
  const int lane = t & 63, wid = t >> 6;

#define EPI(l, CV0, CV1) {                                               \
    float4 v0, v1;                                                       \
    v0.x = Vt * tanhf(i0.x + bc + CV0.x);                                \
    v0.y = Vt * tanhf(i0.y + bc + CV0.y);                                \
    v0.z = Vt * tanhf(i0.z + bc + CV0.z);                                \
    v0.w = Vt * tanhf(i0.w + bc + CV0.w);                                \
    v1.x = Vt * tanhf(i1.x + bc + CV1.x);                                \
    v1.y = Vt * tanhf(i1.y + bc + CV1.y);                                \
    v1.z = Vt * tanhf(i1.z + bc + CV1.z);                                \
    v1.w = Vt * tanhf(i1.w + bc + CV1.w);                                \
    _Pragma("unroll")                                                    \
    for (int off = 32; off > 0; off >>= 1) {                             \
      v0.x += __shfl_down(v0.x, off, 64);                                \
      v0.y += __shfl_down(v0.y, off, 64);                                \
      v0.z += __shfl_down(v0.z, off, 64);                                \
      v0.w += __shfl_down(v0.w, off, 64);                                \
      v1.x += __shfl_down(v1.x, off, 64);                                \
      v1.y += __shfl_down(v1.y, off, 64);                                \
      v1.z += __shfl_down(v1.z, off, 64);                                \
      v1.w += __shfl_down(v1.w, off, 64);                                \
    }                                                                    \
    if (lane == 0) {                                                     \
      red[wid][0] = v0.x; red[wid][1] = v0.y;                            \
      red[wid][2] = v0.z; red[wid][3] = v0.w;                            \
      red[wid][4] = v1.x; red[wid][5] = v1.y;                            \
      red[wid][6] = v1.z; red[wid][7] = v1.w;                            \
    }                                                                    \
    __syncthreads();                                                     \
    if (t < Rr) {                                                        \
      float a = red[0][t] + red[1][t] + red[2][t] + red[3][t];           \
      int b = b0 + t;                                                    \
      if (!maskp[b * Ln + (l)]) a = NEGF;                                \
      a = 10.f * tanhf(a);                                               \
      att_out[b * Ln + (l)] = a;                                         \
    }                                                                    \
    __syncthreads(); }

  EPI(0, c00, c01) EPI(1, c10, c11) EPI(2, c20, c21) EPI(3, c30, c31)
  EPI(4, c40, c41) EPI(5, c50, c51) EPI(6, c60, c61)
}

// ---------------------------------------------------------------------------
__global__ __launch_bounds__(1024) void k_colsum(const float* __restrict__ att,
                                                 float* __restrict__ sbuf) {
  int l = blockIdx.x;     // 0..6
  int t = threadIdx.x;
  double s = 0.0;
  for (int b = t; b < Bn; b += 1024) s += exp((double)att[b * Ln + l]);
  __shared__ double sd[1024];
  sd[t] = s;
  __syncthreads();
  for (int k = 512; k > 0; k >>= 1) {
    if (t < k) sd[t] += sd[t + k];
    __syncthreads();
  }
  if (t == 0) {
    sbuf[l] = (float)sd[0];
    sbuf[7 + l] = (float)log(sd[0]);
  }
}

// ---------------------------------------------------------------------------
__global__ __launch_bounds__(256) void k_sample(const float* __restrict__ att,
                                                const float* __restrict__ sbuf,
                                                const int* __restrict__ maskp,
                                                float* __restrict__ out) {
  int b = blockIdx.x * 256 + threadIdx.x;
  if (b >= Bn) return;
  float best = -3.0e38f;
  int bi = 0;
#pragma unroll
  for (int l = 0; l < Ln; l++) {
    uint32_t n = (uint32_t)(b * Ln + l);
    uint32_t o0, o1;
    threefry2x32(0u, 42u, 0u, n, o0, o1);
    uint32_t bits = o0 ^ o1;
    uint32_t fb = (bits >> 9) | 0x3f800000u;
    float f = __uint_as_float(fb) - 1.0f;
    float u = fmaxf(f, 1.1754943508222875e-38f);
    float g = -logf(-logf(u));
    float y = att[b * Ln + l] - sbuf[7 + l] + g;
    if (y > best) { best = y; bi = l; }
  }
  out[b] = (float)bi;
  out[Bn + b] = expf(att[b * Ln + bi] - sbuf[7 + bi]);
#pragma unroll
  for (int l = 0; l < Ln; l++)
    out[2 * Bn + b * Ln + l] = (float)(maskp[b * Ln + l] - ((l == bi) ? 1 : 0));
}

// ---------------------------------------------------------------------------
extern "C" void kernel_launch(void* const* d_in, const int* in_sizes, int n_in,
                              void* d_out, int out_size, void* d_ws,
                              size_t ws_size, hipStream_t stream) {
  const float* enc   = (const float*)d_in[0];
  const int*   xes   = (const int*)d_in[1];
  const int*   maskp = (const int*)d_in[2];
  const float* W_h   = (const float*)d_in[3];
  const float* W_v   = (const float*)d_in[4];
  const float* Ws_h  = (const float*)d_in[5];
  const float* Ws_v  = (const float*)d_in[6];
  const float* W_e   = (const float*)d_in[7];
  const float* W_in  = (const float*)d_in[8];
  const float* b_in  = (const float*)d_in[9];
  const float* W_ctx = (const float*)d_in[10];
  const float* b_ctx = (const float*)d_in[11];
  const float* V     = (const float*)d_in[12];

  float* ws   = (float*)d_ws;
  float* wt   = ws;                   // 7*65536 floats
  float* att  = ws + 7 * 65536;       // B*7 floats
  float* sbuf = att + Bn * Ln;        // 14 floats

  dim3 gT(256, 7);
  k_prep<<<gT, 256, 0, stream>>>(W_h, W_v, Ws_h, Ws_v, W_e, W_in, W_ctx, wt);
  k_main<<<Bn / Rr, 256, 0, stream>>>(enc, xes, maskp, wt, b_in, b_ctx, V, att);
  k_colsum<<<7, 1024, 0, stream>>>(att, sbuf);
  k_sample<<<Bn / 256, 256, 0, stream>>>(att, sbuf, maskp, (float*)d_out);
}